// Round 12
// baseline (172.726 us; speedup 1.0000x reference)
//
#include <hip/hip_runtime.h>
#include <math.h>

#define BB 4
#define LL 512
#define DD 256
#define HH 8
#define DHH 32
#define NB 12  // BUCKETS + 1 (row 11 is the zero padding row)

// K1: QKV projections (8-row tiles, 768 blocks = 3 blocks/CU). r5/r6 proven.
__global__ __launch_bounds__(256) void qkv_kernel(const float* __restrict__ x,
    const float* __restrict__ Wq, const float* __restrict__ bq,
    const float* __restrict__ Wk, const float* __restrict__ bk,
    const float* __restrict__ Wv, const float* __restrict__ bv,
    const float* __restrict__ uvec, const float* __restrict__ vvec,
    float* __restrict__ Qu, float* __restrict__ Qv,
    float* __restrict__ KT, float* __restrict__ V) {
    __shared__ float xs[8][DD];
    const int mat = blockIdx.x >> 8;          // 0=Q, 1=K, 2=V
    const int r0 = (blockIdx.x & 255) * 8;
    const int t = threadIdx.x;
    const int cg = t & 63, rg = t >> 6;
    const int c0 = cg * 4;
    {
        const float4* xg = (const float4*)(x + r0 * DD);
        float4* xsv = (float4*)&xs[0][0];
        xsv[t] = xg[t];
        xsv[t + 256] = xg[t + 256];
    }
    __syncthreads();
    const float* W    = (mat == 0) ? Wq : (mat == 1) ? Wk : Wv;
    const float* bias = (mat == 0) ? bq : (mat == 1) ? bk : bv;
    float acc[2][4];
#pragma unroll
    for (int r = 0; r < 2; ++r)
#pragma unroll
        for (int c = 0; c < 4; ++c) acc[r][c] = bias[c0 + c];
    for (int i0 = 0; i0 < DD; i0 += 4) {
        float4 wv4[4], xv4[2];
#pragma unroll
        for (int j = 0; j < 4; ++j) wv4[j] = *(const float4*)&W[(i0 + j) * DD + c0];
#pragma unroll
        for (int r = 0; r < 2; ++r) xv4[r] = *(const float4*)&xs[rg * 2 + r][i0];
        const float* wf = (const float*)wv4;
        const float* xf = (const float*)xv4;
#pragma unroll
        for (int r = 0; r < 2; ++r)
#pragma unroll
            for (int j = 0; j < 4; ++j)
#pragma unroll
                for (int c = 0; c < 4; ++c)
                    acc[r][c] = fmaf(xf[r * 4 + j], wf[j * 4 + c], acc[r][c]);
    }
    if (mat == 0) {
        const float s = 0.17677669529663687f;  // 1/sqrt(DH)
        const float4 u4 = *(const float4*)&uvec[c0];
        const float4 v4 = *(const float4*)&vvec[c0];
#pragma unroll
        for (int r = 0; r < 2; ++r) {
            const int row = r0 + rg * 2 + r;
            float4 q = make_float4(acc[r][0] * s, acc[r][1] * s, acc[r][2] * s, acc[r][3] * s);
            *(float4*)&Qu[row * DD + c0] = make_float4(q.x + u4.x, q.y + u4.y, q.z + u4.z, q.w + u4.w);
            *(float4*)&Qv[row * DD + c0] = make_float4(q.x + v4.x, q.y + v4.y, q.z + v4.z, q.w + v4.w);
        }
    } else if (mat == 1) {
        const int b = r0 >> 9;
        const int kb = (r0 & 511) + rg * 2;
#pragma unroll
        for (int c = 0; c < 4; ++c) {
            const int col = c0 + c;
            const int h = col >> 5, dd = col & 31;
            float* p = KT + ((long)((b * HH + h) * DHH + dd)) * LL + kb;
            p[0] = acc[0][c];
            p[1] = acc[1][c];
        }
    } else {
#pragma unroll
        for (int r = 0; r < 2; ++r)
            *(float4*)&V[(r0 + rg * 2 + r) * DD + c0] =
                make_float4(acc[r][0], acc[r][1], acc[r][2], acc[r][3]);
    }
}

// K2: fused rel-P + scores + softmax + attn write + ctx.
// Round-12 (= round-11 resubmit; r11 bench was an infra failure, kernel
// untested). GRANULARITY test: scores has sat at ~44us since r2 while
// traffic (4x), pipe (LDS<->L2), tiling, and residency all varied — and
// reported occupancy NEVER moved off ~35%. Untested axis: 512-thr
// barrier-locked blocks. Now: 2048 blocks x 256 thr (8-row tile/head),
// LDS 17.8KB -> 8 blocks/CU (2048 thr = max); 8 independent blocks/CU
// cover each other's barrier stalls. Phase A = r5-proven 2-row wave body
// (44 VGPR; s-loop outer; nothing new live across the kv[8] windows —
// r1/r3 spill lesson). Per-wave full-row softmax (no psum combine).
// ss swizzle: row q, chunk c, octet o at ss[q*512+c*128+((o^(q>>2))<<3|h4)].
// Phase B: thread=(qt 0..1, dt 0..7, kg 0..15), acc[4][4], sv b128 from ss,
// V[k][4d] direct from global (L2). kg-partials = 16x8x32 floats exactly
// fill the 8x512 ss alias.
__global__ __launch_bounds__(256, 8) void scores_ctx_kernel(const float* __restrict__ Qu,
    const float* __restrict__ Qv, const float* __restrict__ KT,
    const float* __restrict__ rel_table, const int* __restrict__ mask,
    const int* __restrict__ dist, const float* __restrict__ V,
    float* __restrict__ attn, float* __restrict__ ctx) {
    __shared__ float Qs[8][DHH];        // 1 KB
    __shared__ float Ps[8][NB];         // 384 B
    __shared__ float ss[8 * 512];       // 16 KB; preamble aliases Qv8/rels; epilogue aliases partials
    const int blk = blockIdx.x;         // ((b*64 + qt8)*8 + h)
    const int h = blk & 7;
    const int rest = blk >> 3;
    const int qt8 = rest & 63;
    const int b = rest >> 6;
    const int q0 = qt8 * 8;
    const int t = threadIdx.x;
    const int w = t >> 6, l = t & 63;

    float* Qv8  = ss;                   // [8][32]   (dead after Ps compute)
    float* rels = ss + 256;             // [12][33]  (dead after Ps compute)

    {
        const int r = t >> 5, c = t & 31;
        Qs[r][c]         = Qu[(b * LL + q0 + r) * DD + h * DHH + c];
        Qv8[r * DHH + c] = Qv[(b * LL + q0 + r) * DD + h * DHH + c];
    }
    for (int i = t; i < NB * DHH; i += 256) {
        rels[(i >> 5) * 33 + (i & 31)] = rel_table[(i >> 5) * DD + h * DHH + (i & 31)];
    }
    __syncthreads();
    if (t < 8 * NB) {                   // Ps[r][bk] = dot32(Qv8[r], rels[bk])
        const int r = t & 7, bk = t >> 3;
        float a = 0.f;
#pragma unroll
        for (int d = 0; d < DHH; ++d) a = fmaf(Qv8[r * DHH + d], rels[bk * 33 + d], a);
        Ps[r][bk] = a;
    }
    __syncthreads();                    // Qv8/rels dead; ss writable

    // ---- Phase A: wave w owns q rows {2w, 2w+1}, full 512 k (r5 body) ----
    const int r0 = 2 * w;
    const long kbase = (long)(b * HH + h) * DHH * LL;
    float e0[2][4], e1[2][4];
    float sum0 = 0.f, sum1 = 0.f;
#pragma unroll
    for (int s = 0; s < 2; ++s) {
        const int k0 = 4 * l + 256 * s;
        const int4 dx0 = *(const int4*)&dist[(b * LL + q0 + r0) * LL + k0];
        const int4 dx1 = *(const int4*)&dist[(b * LL + q0 + r0 + 1) * LL + k0];
        const int4 mx0 = *(const int4*)&mask[(b * LL + q0 + r0) * LL + k0];
        const int4 mx1 = *(const int4*)&mask[(b * LL + q0 + r0 + 1) * LL + k0];
        float s0[4], s1[4];
        s0[0] = Ps[r0][dx0.x]; s0[1] = Ps[r0][dx0.y]; s0[2] = Ps[r0][dx0.z]; s0[3] = Ps[r0][dx0.w];
        s1[0] = Ps[r0 + 1][dx1.x]; s1[1] = Ps[r0 + 1][dx1.y]; s1[2] = Ps[r0 + 1][dx1.z]; s1[3] = Ps[r0 + 1][dx1.w];
#pragma unroll
        for (int d8 = 0; d8 < DHH; d8 += 8) {
            float4 kv[8];                        // 8 loads in flight (L2)
#pragma unroll
            for (int j = 0; j < 8; ++j)
                kv[j] = *(const float4*)&KT[kbase + (long)(d8 + j) * LL + k0];
            const float4 q0a = *(const float4*)&Qs[r0][d8];
            const float4 q0b = *(const float4*)&Qs[r0][d8 + 4];
            const float4 q1a = *(const float4*)&Qs[r0 + 1][d8];
            const float4 q1b = *(const float4*)&Qs[r0 + 1][d8 + 4];
            const float* qa0 = (const float*)&q0a;
            const float* qb0 = (const float*)&q0b;
            const float* qa1 = (const float*)&q1a;
            const float* qb1 = (const float*)&q1b;
#pragma unroll
            for (int j = 0; j < 4; ++j) {
                s0[0] = fmaf(qa0[j], kv[j].x, s0[0]);
                s0[1] = fmaf(qa0[j], kv[j].y, s0[1]);
                s0[2] = fmaf(qa0[j], kv[j].z, s0[2]);
                s0[3] = fmaf(qa0[j], kv[j].w, s0[3]);
                s1[0] = fmaf(qa1[j], kv[j].x, s1[0]);
                s1[1] = fmaf(qa1[j], kv[j].y, s1[1]);
                s1[2] = fmaf(qa1[j], kv[j].z, s1[2]);
                s1[3] = fmaf(qa1[j], kv[j].w, s1[3]);
            }
#pragma unroll
            for (int j = 0; j < 4; ++j) {
                s0[0] = fmaf(qb0[j], kv[j + 4].x, s0[0]);
                s0[1] = fmaf(qb0[j], kv[j + 4].y, s0[1]);
                s0[2] = fmaf(qb0[j], kv[j + 4].z, s0[2]);
                s0[3] = fmaf(qb0[j], kv[j + 4].w, s0[3]);
                s1[0] = fmaf(qb1[j], kv[j + 4].x, s1[0]);
                s1[1] = fmaf(qb1[j], kv[j + 4].y, s1[1]);
                s1[2] = fmaf(qb1[j], kv[j + 4].z, s1[2]);
                s1[3] = fmaf(qb1[j], kv[j + 4].w, s1[3]);
            }
        }
        e0[s][0] = mx0.x ? 0.f : __expf(s0[0]);
        e0[s][1] = mx0.y ? 0.f : __expf(s0[1]);
        e0[s][2] = mx0.z ? 0.f : __expf(s0[2]);
        e0[s][3] = mx0.w ? 0.f : __expf(s0[3]);
        e1[s][0] = mx1.x ? 0.f : __expf(s1[0]);
        e1[s][1] = mx1.y ? 0.f : __expf(s1[1]);
        e1[s][2] = mx1.z ? 0.f : __expf(s1[2]);
        e1[s][3] = mx1.w ? 0.f : __expf(s1[3]);
        sum0 += (e0[s][0] + e0[s][1]) + (e0[s][2] + e0[s][3]);
        sum1 += (e1[s][0] + e1[s][1]) + (e1[s][2] + e1[s][3]);
    }
    for (int off = 32; off > 0; off >>= 1) {
        sum0 += __shfl_xor(sum0, off);
        sum1 += __shfl_xor(sum1, off);
    }
    const float inv0 = 1.0f / sum0, inv1 = 1.0f / sum1;
    float* a0 = attn + ((long)(b * HH + h) * LL + q0 + r0) * LL;
    float* a1 = a0 + LL;
#pragma unroll
    for (int s = 0; s < 2; ++s) {
        const int k0 = 4 * l + 256 * s;
        const int ch = k0 >> 7;
        const int oct = (k0 & 127) >> 3;
        const int h4 = k0 & 4;
        const float4 o0 = make_float4(e0[s][0] * inv0, e0[s][1] * inv0, e0[s][2] * inv0, e0[s][3] * inv0);
        const float4 o1 = make_float4(e1[s][0] * inv1, e1[s][1] * inv1, e1[s][2] * inv1, e1[s][3] * inv1);
        *(float4*)&a0[k0] = o0;
        *(float4*)&a1[k0] = o1;
        *(float4*)&ss[r0 * 512 + ch * 128 + (((oct ^ (r0 >> 2)) << 3) | h4)] = o0;
        *(float4*)&ss[(r0 + 1) * 512 + ch * 128 + (((oct ^ ((r0 + 1) >> 2)) << 3) | h4)] = o1;
    }

    // ---- Phase B: ctx via 4q x 4d register tiles; V direct from global (L2) ----
    const int qt = t & 1;               // q-tile (rows 4qt..4qt+3); q>>2 == qt
    const int dt = (t >> 1) & 7;        // d-tile (cols 4dt..4dt+3)
    const int kg = t >> 4;              // k-octet within chunk (0..15)
    const float* vbase = V + (long)b * LL * DD + h * DHH + dt * 4;
    float acc[4][4];
#pragma unroll
    for (int i = 0; i < 4; ++i)
#pragma unroll
        for (int jd = 0; jd < 4; ++jd) acc[i][jd] = 0.f;
    __syncthreads();                    // ss fully written
#pragma unroll 1
    for (int c = 0; c < 4; ++c) {
#pragma unroll
        for (int ki = 0; ki < 2; ++ki) {
            float4 sv[4];               // 4 consecutive k of rows qt*4..qt*4+3
#pragma unroll
            for (int i = 0; i < 4; ++i)
                sv[i] = *(const float4*)&ss[(qt * 4 + i) * 512 + c * 128 + (((kg ^ qt) << 3) | (ki << 2))];
#pragma unroll
            for (int j = 0; j < 4; ++j) {
                const int k = c * 128 + (kg << 3) + (ki << 2) + j;
                const float4 vf = *(const float4*)&vbase[k * DD];
                const float w0 = ((const float*)&sv[0])[j];
                const float w1 = ((const float*)&sv[1])[j];
                const float w2 = ((const float*)&sv[2])[j];
                const float w3 = ((const float*)&sv[3])[j];
                acc[0][0] = fmaf(w0, vf.x, acc[0][0]); acc[0][1] = fmaf(w0, vf.y, acc[0][1]);
                acc[0][2] = fmaf(w0, vf.z, acc[0][2]); acc[0][3] = fmaf(w0, vf.w, acc[0][3]);
                acc[1][0] = fmaf(w1, vf.x, acc[1][0]); acc[1][1] = fmaf(w1, vf.y, acc[1][1]);
                acc[1][2] = fmaf(w1, vf.z, acc[1][2]); acc[1][3] = fmaf(w1, vf.w, acc[1][3]);
                acc[2][0] = fmaf(w2, vf.x, acc[2][0]); acc[2][1] = fmaf(w2, vf.y, acc[2][1]);
                acc[2][2] = fmaf(w2, vf.z, acc[2][2]); acc[2][3] = fmaf(w2, vf.w, acc[2][3]);
                acc[3][0] = fmaf(w3, vf.x, acc[3][0]); acc[3][1] = fmaf(w3, vf.y, acc[3][1]);
                acc[3][2] = fmaf(w3, vf.z, acc[3][2]); acc[3][3] = fmaf(w3, vf.w, acc[3][3]);
            }
        }
    }
    // kg-reduction: partials[kg][q][d] = 16*8*32 floats exactly fill ss.
    __syncthreads();                    // all phase-B ss reads done
#pragma unroll
    for (int i = 0; i < 4; ++i)
        *(float4*)&ss[kg * 256 + (qt * 4 + i) * 32 + dt * 4] =
            make_float4(acc[i][0], acc[i][1], acc[i][2], acc[i][3]);
    __syncthreads();
    {
        const int qr = t >> 5, dr = t & 31;   // 8 rows x 32 d = 256 threads
        float r = 0.f;
#pragma unroll
        for (int g = 0; g < 16; ++g) r += ss[g * 256 + qr * 32 + dr];
        ctx[(b * LL + q0 + qr) * DD + h * DHH + dr] = r;
    }
}

// K3: output projection. Block = 4 rows (512 blocks = 2/CU); 8 W loads in
// flight. (r6 proven form.)
__global__ __launch_bounds__(256) void outproj_kernel(const float* __restrict__ ctx,
    const float* __restrict__ Wo, const float* __restrict__ bo,
    float* __restrict__ out) {
    __shared__ float xs[4][DD];
    const int r0 = blockIdx.x * 4;
    const int t = threadIdx.x;
    const int rg = t >> 6;
    const int c0 = (t & 63) * 4;
    ((float4*)&xs[0][0])[t] = ((const float4*)(ctx + r0 * DD))[t];
    __syncthreads();
    float4 acc = *(const float4*)&bo[c0];
    for (int i0 = 0; i0 < DD; i0 += 8) {
        float4 wv[8];
#pragma unroll
        for (int j = 0; j < 8; ++j) wv[j] = *(const float4*)&Wo[(i0 + j) * DD + c0];
        const float4 x0 = *(const float4*)&xs[rg][i0];
        const float4 x1 = *(const float4*)&xs[rg][i0 + 4];
        const float* xf0 = (const float*)&x0;
        const float* xf1 = (const float*)&x1;
#pragma unroll
        for (int j = 0; j < 4; ++j) {
            acc.x = fmaf(xf0[j], wv[j].x, acc.x);
            acc.y = fmaf(xf0[j], wv[j].y, acc.y);
            acc.z = fmaf(xf0[j], wv[j].z, acc.z);
            acc.w = fmaf(xf0[j], wv[j].w, acc.w);
        }
#pragma unroll
        for (int j = 0; j < 4; ++j) {
            acc.x = fmaf(xf1[j], wv[j + 4].x, acc.x);
            acc.y = fmaf(xf1[j], wv[j + 4].y, acc.y);
            acc.z = fmaf(xf1[j], wv[j + 4].z, acc.z);
            acc.w = fmaf(xf1[j], wv[j + 4].w, acc.w);
        }
    }
    *(float4*)&out[(r0 + rg) * DD + c0] = acc;
}

extern "C" void kernel_launch(void* const* d_in, const int* in_sizes, int n_in,
                              void* d_out, int out_size, void* d_ws, size_t ws_size,
                              hipStream_t stream) {
    const float* x    = (const float*)d_in[0];
    const int* mk     = (const int*)d_in[1];   // jax bool -> int32
    const int* dist   = (const int*)d_in[2];
    const float* Wq = (const float*)d_in[3];
    const float* bq = (const float*)d_in[4];
    const float* Wk = (const float*)d_in[5];
    const float* bk = (const float*)d_in[6];
    const float* Wv = (const float*)d_in[7];
    const float* bv = (const float*)d_in[8];
    const float* Wo = (const float*)d_in[9];
    const float* bo = (const float*)d_in[10];
    const float* rel_table = (const float*)d_in[11];
    const float* uvec = (const float*)d_in[12];
    const float* vvec = (const float*)d_in[13];

    float* out  = (float*)d_out;                 // (B,L,D)
    float* attn = out + BB * LL * DD;            // (B,H,L,L)

    float* Qu = (float*)d_ws;                    // q/sqrt(dh) + u
    float* Qv = Qu + BB * LL * DD;               // q/sqrt(dh) + v
    float* KT = Qv + BB * LL * DD;               // [B][H][DH][L]
    float* V  = KT + BB * LL * DD;               // [B][L][D]
    float* C  = V + BB * LL * DD;                // ctx (B,L,D); 10.5 MB ws total

    qkv_kernel<<<3 * 256, 256, 0, stream>>>(x, Wq, bq, Wk, bk, Wv, bv, uvec, vvec,
                                            Qu, Qv, KT, V);
    scores_ctx_kernel<<<BB * (LL / 8) * HH, 256, 0, stream>>>(Qu, Qv, KT, rel_table,
                                                              mk, dist, V, attn, C);
    outproj_kernel<<<BB * LL / 4, 256, 0, stream>>>(C, Wo, bo, out);
}

// Round 13
// 163.276 us; speedup vs baseline: 1.0579x; 1.0579x over previous
//
#include <hip/hip_runtime.h>
#include <math.h>

#define BB 4
#define LL 512
#define DD 256
#define HH 8
#define DHH 32
#define NB 12  // BUCKETS + 1 (row 11 is the zero padding row)

// K1: QKV projections (8-row tiles, 768 blocks = 3 blocks/CU).
// Thread = 2 rows x 4 cols. mat0 writes Qu=q/sqrt(dh)+u, Qv=q/sqrt(dh)+v;
// mat1 writes KT[b][h][d][k]; mat2 writes V[b][k][d].
__global__ __launch_bounds__(256) void qkv_kernel(const float* __restrict__ x,
    const float* __restrict__ Wq, const float* __restrict__ bq,
    const float* __restrict__ Wk, const float* __restrict__ bk,
    const float* __restrict__ Wv, const float* __restrict__ bv,
    const float* __restrict__ uvec, const float* __restrict__ vvec,
    float* __restrict__ Qu, float* __restrict__ Qv,
    float* __restrict__ KT, float* __restrict__ V) {
    __shared__ float xs[8][DD];
    const int mat = blockIdx.x >> 8;          // 0=Q, 1=K, 2=V
    const int r0 = (blockIdx.x & 255) * 8;
    const int t = threadIdx.x;
    const int cg = t & 63, rg = t >> 6;
    const int c0 = cg * 4;
    {
        const float4* xg = (const float4*)(x + r0 * DD);
        float4* xsv = (float4*)&xs[0][0];
        xsv[t] = xg[t];
        xsv[t + 256] = xg[t + 256];
    }
    __syncthreads();
    const float* W    = (mat == 0) ? Wq : (mat == 1) ? Wk : Wv;
    const float* bias = (mat == 0) ? bq : (mat == 1) ? bk : bv;
    float acc[2][4];
#pragma unroll
    for (int r = 0; r < 2; ++r)
#pragma unroll
        for (int c = 0; c < 4; ++c) acc[r][c] = bias[c0 + c];
    for (int i0 = 0; i0 < DD; i0 += 4) {
        float4 wv4[4], xv4[2];
#pragma unroll
        for (int j = 0; j < 4; ++j) wv4[j] = *(const float4*)&W[(i0 + j) * DD + c0];
#pragma unroll
        for (int r = 0; r < 2; ++r) xv4[r] = *(const float4*)&xs[rg * 2 + r][i0];
        const float* wf = (const float*)wv4;
        const float* xf = (const float*)xv4;
#pragma unroll
        for (int r = 0; r < 2; ++r)
#pragma unroll
            for (int j = 0; j < 4; ++j)
#pragma unroll
                for (int c = 0; c < 4; ++c)
                    acc[r][c] = fmaf(xf[r * 4 + j], wf[j * 4 + c], acc[r][c]);
    }
    if (mat == 0) {
        const float s = 0.17677669529663687f;  // 1/sqrt(DH)
        const float4 u4 = *(const float4*)&uvec[c0];
        const float4 v4 = *(const float4*)&vvec[c0];
#pragma unroll
        for (int r = 0; r < 2; ++r) {
            const int row = r0 + rg * 2 + r;
            float4 q = make_float4(acc[r][0] * s, acc[r][1] * s, acc[r][2] * s, acc[r][3] * s);
            *(float4*)&Qu[row * DD + c0] = make_float4(q.x + u4.x, q.y + u4.y, q.z + u4.z, q.w + u4.w);
            *(float4*)&Qv[row * DD + c0] = make_float4(q.x + v4.x, q.y + v4.y, q.z + v4.z, q.w + v4.w);
        }
    } else if (mat == 1) {
        const int b = r0 >> 9;
        const int kb = (r0 & 511) + rg * 2;
#pragma unroll
        for (int c = 0; c < 4; ++c) {
            const int col = c0 + c;
            const int h = col >> 5, dd = col & 31;
            float* p = KT + ((long)((b * HH + h) * DHH + dd)) * LL + kb;
            p[0] = acc[0][c];
            p[1] = acc[1][c];
        }
    } else {
#pragma unroll
        for (int r = 0; r < 2; ++r)
            *(float4*)&V[(r0 + rg * 2 + r) * DD + c0] =
                make_float4(acc[r][0], acc[r][1], acc[r][2], acc[r][3]);
    }
}

// K2: fused rel-P + scores + softmax + attn write + ctx.
// Session-best configuration (round 6, 164.5us total, scores 44.1us).
// Phase A reads K from LDS-staged half-tiles Ks[32][256] aliased onto ss
// (dead during phase A; barrier after compute and before ss writes makes the
// alias safe). Phase-A register structure is the proven r2/r5 body (kv[8]
// window, s outer) — rounds 1/3/4 proved restructuring it (or wrapping it in
// a tile loop) spills ~0.5-1.6KB/thread (WRITE_SIZE 6x). Staging: flat
// f=(j*512+t)*4; each wave reads one contiguous 1KB row-half (coalesced);
// ds_write_b128 2-way. kv source: ds_read_b128 from Ks, word addr
// (d8+j)*256+4l -> banks {0,4..28}x2 = 2-way free.
// ss swizzle: element k of row q, chunk c at
//   ss[q*512 + c*128 + (((k>>3)^(q>>2))<<3) + (k&7)].
// Phase B: thread=(qt,dt,kg) 4qx4d register tile, sv from swizzled ss b128,
// V[k][4d] float4 direct from global (L2-resident). kg-partials reduced via
// the dead ss alias. LDS 35.8KB -> 4 blocks/CU full residency.
__global__ __launch_bounds__(512, 4) void scores_ctx_kernel(const float* __restrict__ Qu,
    const float* __restrict__ Qv, const float* __restrict__ KT,
    const float* __restrict__ rel_table, const int* __restrict__ mask,
    const int* __restrict__ dist, const float* __restrict__ V,
    float* __restrict__ attn, float* __restrict__ ctx) {
    __shared__ float Qs[16][DHH];
    __shared__ float Ps[16][NB];
    __shared__ float ss[16 * 512];      // 32KB; aliases: preamble Qv8/rels, phase-A Ks, epilogue partials
    const int blk = blockIdx.x;         // ((b*32 + qt16)*8 + h)
    const int h = blk & 7;
    const int rest = blk >> 3;
    const int qt16 = rest & 31;
    const int b = rest >> 5;
    const int q0 = qt16 * 16;
    const int t = threadIdx.x;
    const int w = t >> 6, l = t & 63;

    float* Qv8  = ss;                   // [16][32]  (dead after Ps compute)
    float* rels = ss + 512;             // [12][33]  (dead after Ps compute)
    float* Ks   = ss;                   // [32][256] k-half of KT (dead before ss writes)

    {
        const int r = t >> 5, c = t & 31;
        Qs[r][c]          = Qu[(b * LL + q0 + r) * DD + h * DHH + c];
        Qv8[r * DHH + c]  = Qv[(b * LL + q0 + r) * DD + h * DHH + c];
    }
    if (t < NB * DHH) {
        rels[(t >> 5) * 33 + (t & 31)] = rel_table[(t >> 5) * DD + h * DHH + (t & 31)];
    }
    __syncthreads();
    if (t < 16 * NB) {                  // Ps[r][bk] = dot32(Qv8[r], rels[bk])
        const int bk = t >> 4, r = t & 15;
        float a = 0.f;
#pragma unroll
        for (int d = 0; d < DHH; ++d) a = fmaf(Qv8[r * DHH + d], rels[bk * 33 + d], a);
        Ps[r][bk] = a;
    }
    __syncthreads();                    // Qv8/rels dead; ss region (Ks) writable

    // ---- Phase A: scores + softmax; K from LDS-staged half-tiles ----
    const int r0 = 2 * w;
    const long kbase = (long)(b * HH + h) * DHH * LL;
    float e0[2][4], e1[2][4];
    float sum0 = 0.f, sum1 = 0.f;
#pragma unroll
    for (int s = 0; s < 2; ++s) {
        if (s) __syncthreads();         // all Ks(s=0) reads done before restage
        {   // stage KT[d][s*256 + kk] -> Ks[d*256 + kk]; flat, fully coalesced
#pragma unroll
            for (int j = 0; j < 4; ++j) {
                const int f = (j * 512 + t) * 4;    // flat float idx; d=f>>8, kk=f&255
                const float4 kv4 = *(const float4*)&KT[kbase + (long)(f >> 8) * LL + s * 256 + (f & 255)];
                *(float4*)&Ks[f] = kv4;
            }
        }
        __syncthreads();                // Ks ready
        const int k0 = 4 * l + 256 * s;
        const int4 dx0 = *(const int4*)&dist[(b * LL + q0 + r0) * LL + k0];
        const int4 dx1 = *(const int4*)&dist[(b * LL + q0 + r0 + 1) * LL + k0];
        const int4 mx0 = *(const int4*)&mask[(b * LL + q0 + r0) * LL + k0];
        const int4 mx1 = *(const int4*)&mask[(b * LL + q0 + r0 + 1) * LL + k0];
        float s0[4], s1[4];
        s0[0] = Ps[r0][dx0.x]; s0[1] = Ps[r0][dx0.y]; s0[2] = Ps[r0][dx0.z]; s0[3] = Ps[r0][dx0.w];
        s1[0] = Ps[r0 + 1][dx1.x]; s1[1] = Ps[r0 + 1][dx1.y]; s1[2] = Ps[r0 + 1][dx1.z]; s1[3] = Ps[r0 + 1][dx1.w];
#pragma unroll
        for (int d8 = 0; d8 < DHH; d8 += 8) {
            float4 kv[8];                        // 8 LDS reads in flight
#pragma unroll
            for (int j = 0; j < 8; ++j)
                kv[j] = *(const float4*)&Ks[(d8 + j) * 256 + 4 * l];
            const float4 q0a = *(const float4*)&Qs[r0][d8];
            const float4 q0b = *(const float4*)&Qs[r0][d8 + 4];
            const float4 q1a = *(const float4*)&Qs[r0 + 1][d8];
            const float4 q1b = *(const float4*)&Qs[r0 + 1][d8 + 4];
            const float* qa0 = (const float*)&q0a;
            const float* qb0 = (const float*)&q0b;
            const float* qa1 = (const float*)&q1a;
            const float* qb1 = (const float*)&q1b;
#pragma unroll
            for (int j = 0; j < 4; ++j) {
                s0[0] = fmaf(qa0[j], kv[j].x, s0[0]);
                s0[1] = fmaf(qa0[j], kv[j].y, s0[1]);
                s0[2] = fmaf(qa0[j], kv[j].z, s0[2]);
                s0[3] = fmaf(qa0[j], kv[j].w, s0[3]);
                s1[0] = fmaf(qa1[j], kv[j].x, s1[0]);
                s1[1] = fmaf(qa1[j], kv[j].y, s1[1]);
                s1[2] = fmaf(qa1[j], kv[j].z, s1[2]);
                s1[3] = fmaf(qa1[j], kv[j].w, s1[3]);
            }
#pragma unroll
            for (int j = 0; j < 4; ++j) {
                s0[0] = fmaf(qb0[j], kv[j + 4].x, s0[0]);
                s0[1] = fmaf(qb0[j], kv[j + 4].y, s0[1]);
                s0[2] = fmaf(qb0[j], kv[j + 4].z, s0[2]);
                s0[3] = fmaf(qb0[j], kv[j + 4].w, s0[3]);
                s1[0] = fmaf(qb1[j], kv[j + 4].x, s1[0]);
                s1[1] = fmaf(qb1[j], kv[j + 4].y, s1[1]);
                s1[2] = fmaf(qb1[j], kv[j + 4].z, s1[2]);
                s1[3] = fmaf(qb1[j], kv[j + 4].w, s1[3]);
            }
        }
        e0[s][0] = mx0.x ? 0.f : __expf(s0[0]);
        e0[s][1] = mx0.y ? 0.f : __expf(s0[1]);
        e0[s][2] = mx0.z ? 0.f : __expf(s0[2]);
        e0[s][3] = mx0.w ? 0.f : __expf(s0[3]);
        e1[s][0] = mx1.x ? 0.f : __expf(s1[0]);
        e1[s][1] = mx1.y ? 0.f : __expf(s1[1]);
        e1[s][2] = mx1.z ? 0.f : __expf(s1[2]);
        e1[s][3] = mx1.w ? 0.f : __expf(s1[3]);
        sum0 += (e0[s][0] + e0[s][1]) + (e0[s][2] + e0[s][3]);
        sum1 += (e1[s][0] + e1[s][1]) + (e1[s][2] + e1[s][3]);
    }
    for (int off = 32; off > 0; off >>= 1) {
        sum0 += __shfl_xor(sum0, off);
        sum1 += __shfl_xor(sum1, off);
    }
    const float inv0 = 1.0f / sum0, inv1 = 1.0f / sum1;
    __syncthreads();                    // all Ks reads done before ss overwrite
    float* a0 = attn + ((long)(b * HH + h) * LL + q0 + r0) * LL;
    float* a1 = a0 + LL;
#pragma unroll
    for (int s = 0; s < 2; ++s) {
        const int k0 = 4 * l + 256 * s;
        const int ch = k0 >> 7;
        const int oct = (k0 & 127) >> 3;
        const int h4 = k0 & 4;
        const float4 o0 = make_float4(e0[s][0] * inv0, e0[s][1] * inv0, e0[s][2] * inv0, e0[s][3] * inv0);
        const float4 o1 = make_float4(e1[s][0] * inv1, e1[s][1] * inv1, e1[s][2] * inv1, e1[s][3] * inv1);
        *(float4*)&a0[k0] = o0;
        *(float4*)&a1[k0] = o1;
        *(float4*)&ss[r0 * 512 + ch * 128 + (((oct ^ (r0 >> 2)) << 3) | h4)] = o0;
        *(float4*)&ss[(r0 + 1) * 512 + ch * 128 + (((oct ^ ((r0 + 1) >> 2)) << 3) | h4)] = o1;
    }

    // ---- Phase B: ctx via 4q x 4d register tiles; V direct from global (L2) ----
    const int qt = t & 3;               // q-tile (rows 4qt..4qt+3); == q>>2 for its rows
    const int dt = (t >> 2) & 7;        // d-tile (cols 4dt..4dt+3)
    const int kg = t >> 5;              // k-octet within chunk (0..15)
    const float* vbase = V + (long)b * LL * DD + h * DHH + dt * 4;
    float acc[4][4];
#pragma unroll
    for (int i = 0; i < 4; ++i)
#pragma unroll
        for (int jd = 0; jd < 4; ++jd) acc[i][jd] = 0.f;
    __syncthreads();                    // ss fully written
#pragma unroll 1
    for (int c = 0; c < 4; ++c) {
#pragma unroll
        for (int ki = 0; ki < 2; ++ki) {
            float4 sv[4];               // 4 consecutive k of rows qt*4..qt*4+3
#pragma unroll
            for (int i = 0; i < 4; ++i)
                sv[i] = *(const float4*)&ss[(qt * 4 + i) * 512 + c * 128 + (((kg ^ qt) << 3) | (ki << 2))];
#pragma unroll
            for (int j = 0; j < 4; ++j) {
                const int k = c * 128 + (kg << 3) + (ki << 2) + j;
                const float4 vf = *(const float4*)&vbase[k * DD];
                const float w0 = ((const float*)&sv[0])[j];
                const float w1 = ((const float*)&sv[1])[j];
                const float w2 = ((const float*)&sv[2])[j];
                const float w3 = ((const float*)&sv[3])[j];
                acc[0][0] = fmaf(w0, vf.x, acc[0][0]); acc[0][1] = fmaf(w0, vf.y, acc[0][1]);
                acc[0][2] = fmaf(w0, vf.z, acc[0][2]); acc[0][3] = fmaf(w0, vf.w, acc[0][3]);
                acc[1][0] = fmaf(w1, vf.x, acc[1][0]); acc[1][1] = fmaf(w1, vf.y, acc[1][1]);
                acc[1][2] = fmaf(w1, vf.z, acc[1][2]); acc[1][3] = fmaf(w1, vf.w, acc[1][3]);
                acc[2][0] = fmaf(w2, vf.x, acc[2][0]); acc[2][1] = fmaf(w2, vf.y, acc[2][1]);
                acc[2][2] = fmaf(w2, vf.z, acc[2][2]); acc[2][3] = fmaf(w2, vf.w, acc[2][3]);
                acc[3][0] = fmaf(w3, vf.x, acc[3][0]); acc[3][1] = fmaf(w3, vf.y, acc[3][1]);
                acc[3][2] = fmaf(w3, vf.z, acc[3][2]); acc[3][3] = fmaf(w3, vf.w, acc[3][3]);
            }
        }
    }
    // kg-reduction: partials[kg][q][d] reuse ss (exactly 16*512 floats).
    // b128 writes: start bank = dt*4 -> 8 starts x 8 lanes -> uniform.
    __syncthreads();                    // all phase-B ss reads done
#pragma unroll
    for (int i = 0; i < 4; ++i)
        *(float4*)&ss[kg * 512 + (qt * 4 + i) * 32 + dt * 4] =
            make_float4(acc[i][0], acc[i][1], acc[i][2], acc[i][3]);
    __syncthreads();
    {
        const int qr = t >> 5, dr = t & 31;   // reads: bank = dr -> 2-way (free)
        float r = 0.f;
#pragma unroll
        for (int kg2 = 0; kg2 < 16; ++kg2) r += ss[kg2 * 512 + qr * 32 + dr];
        ctx[(b * LL + q0 + qr) * DD + h * DHH + dr] = r;
    }
}

// K3: output projection. Block = 4 rows (512 blocks = 2/CU); thread = 1 row x
// 4 cols; 8 W loads in flight.
__global__ __launch_bounds__(256) void outproj_kernel(const float* __restrict__ ctx,
    const float* __restrict__ Wo, const float* __restrict__ bo,
    float* __restrict__ out) {
    __shared__ float xs[4][DD];
    const int r0 = blockIdx.x * 4;
    const int t = threadIdx.x;
    const int rg = t >> 6;
    const int c0 = (t & 63) * 4;
    ((float4*)&xs[0][0])[t] = ((const float4*)(ctx + r0 * DD))[t];
    __syncthreads();
    float4 acc = *(const float4*)&bo[c0];
    for (int i0 = 0; i0 < DD; i0 += 8) {
        float4 wv[8];
#pragma unroll
        for (int j = 0; j < 8; ++j) wv[j] = *(const float4*)&Wo[(i0 + j) * DD + c0];
        const float4 x0 = *(const float4*)&xs[rg][i0];
        const float4 x1 = *(const float4*)&xs[rg][i0 + 4];
        const float* xf0 = (const float*)&x0;
        const float* xf1 = (const float*)&x1;
#pragma unroll
        for (int j = 0; j < 4; ++j) {
            acc.x = fmaf(xf0[j], wv[j].x, acc.x);
            acc.y = fmaf(xf0[j], wv[j].y, acc.y);
            acc.z = fmaf(xf0[j], wv[j].z, acc.z);
            acc.w = fmaf(xf0[j], wv[j].w, acc.w);
        }
#pragma unroll
        for (int j = 0; j < 4; ++j) {
            acc.x = fmaf(xf1[j], wv[j + 4].x, acc.x);
            acc.y = fmaf(xf1[j], wv[j + 4].y, acc.y);
            acc.z = fmaf(xf1[j], wv[j + 4].z, acc.z);
            acc.w = fmaf(xf1[j], wv[j + 4].w, acc.w);
        }
    }
    *(float4*)&out[(r0 + rg) * DD + c0] = acc;
}

extern "C" void kernel_launch(void* const* d_in, const int* in_sizes, int n_in,
                              void* d_out, int out_size, void* d_ws, size_t ws_size,
                              hipStream_t stream) {
    const float* x    = (const float*)d_in[0];
    const int* mk     = (const int*)d_in[1];   // jax bool -> int32
    const int* dist   = (const int*)d_in[2];
    const float* Wq = (const float*)d_in[3];
    const float* bq = (const float*)d_in[4];
    const float* Wk = (const float*)d_in[5];
    const float* bk = (const float*)d_in[6];
    const float* Wv = (const float*)d_in[7];
    const float* bv = (const float*)d_in[8];
    const float* Wo = (const float*)d_in[9];
    const float* bo = (const float*)d_in[10];
    const float* rel_table = (const float*)d_in[11];
    const float* uvec = (const float*)d_in[12];
    const float* vvec = (const float*)d_in[13];

    float* out  = (float*)d_out;                 // (B,L,D)
    float* attn = out + BB * LL * DD;            // (B,H,L,L)

    float* Qu = (float*)d_ws;                    // q/sqrt(dh) + u
    float* Qv = Qu + BB * LL * DD;               // q/sqrt(dh) + v
    float* KT = Qv + BB * LL * DD;               // [B][H][DH][L]
    float* V  = KT + BB * LL * DD;               // [B][L][D]
    float* C  = V + BB * LL * DD;                // ctx (B,L,D); 10.5 MB ws total

    qkv_kernel<<<3 * 256, 256, 0, stream>>>(x, Wq, bq, Wk, bk, Wv, bv, uvec, vvec,
                                            Qu, Qv, KT, V);
    scores_ctx_kernel<<<BB * (LL / 16) * HH, 512, 0, stream>>>(Qu, Qv, KT, rel_table,
                                                               mk, dist, V, attn, C);
    outproj_kernel<<<BB * LL / 4, 256, 0, stream>>>(C, Wo, bo, out);
}